// Round 10
// baseline (108.374 us; speedup 1.0000x reference)
//
#include <hip/hip_runtime.h>
#include <hip/hip_bf16.h>

#define NODES 50000
#define NA    65
#define NDEG  32

// Inputs f32 (R2 probe). Output f32.
// R9 -> R10: STREAM corr, don't gather it.
//   Evidence: harness re-poisons 268MB (> 256MB L3) before every timed
//   launch -> caches fully cold each iteration (FETCH=22MB/iter). R7/R8/R9
//   all kept a dependent idx->gather pointer-chase into cold HBM and all
//   pinned at ~26us. Random 32-of-65 gathers touch every line of a node's
//   520B corr row anyway, so streaming fetches the SAME bytes -- but as
//   independent coalesced float4 streams (pipelined misses) instead of
//   serialized dependent ones. Gather moves into LDS (~120cyc).
//   Block = 256 thr = 4 waves = 32 nodes; corr rows 32x130 floats -> one
//   contiguous 16.6KB block span staged to LDS. idx loads issue upfront and
//   ride out their latency during staging + barrier.
//   Layer 2 stays one v_mfma_f32_32x32x16_bf16 per node (M=nei,N=ch,K=hid).

typedef float v2f __attribute__((ext_vector_type(2)));
typedef __attribute__((ext_vector_type(8))) short short8;     // 8 bf16 = 4 VGPRs
typedef __attribute__((ext_vector_type(16))) float f32x16;    // MFMA C/D

static __device__ __forceinline__ v2f pk_fma(v2f a, v2f b, v2f c) {
    return __builtin_elementwise_fma(a, b, c);
}
static __device__ __forceinline__ v2f pk_max(v2f a, v2f b) {
    return __builtin_elementwise_max(a, b);
}

#define ROWF 130                     // floats per corr row (65 * 2)
#define CORR_F4 1625000              // total float4 in corr = NODES*130/4

__global__ __launch_bounds__(256, 1) void fused_kernel(
    const float* __restrict__ corr,   // (N, 65, 2)
    const int*   __restrict__ nei,    // (N, 32, 3)
    const float* __restrict__ W_se,   // (2, 32)
    const float* __restrict__ b_se,   // (32)
    const float* __restrict__ W1,     // (32, 16)
    const float* __restrict__ b1,     // (16)
    const float* __restrict__ W2,     // (16, 32)
    const float* __restrict__ b2,     // (32)
    float* __restrict__ out)          // (N, 32)
{
    __shared__ __align__(16) float fold[48];
    __shared__ __align__(16) float ldsCorr[32 * ROWF];   // 16,640 B

    int t     = threadIdx.x;
    int lane  = t & 63;
    int w     = t >> 6;              // wave 0..3 -> nodes w*8 .. w*8+7
    int col   = lane & 31;           // m (neighbor) for A, n (channel) for B/C
    int khalf = lane >> 5;           // k-chunk: 0 -> k 0..7, 1 -> k 8..15
    int nb    = blockIdx.x * 32;     // first node of block
    int nbase = nb + w * 8;

    // ---- idx loads first: independent, fly during staging + barrier ----
    int idxv[8];
#pragma unroll
    for (int i = 0; i < 8; ++i) {
        int node = nbase + i; if (node > NODES - 1) node = NODES - 1;
        idxv[i] = nei[((size_t)node * NDEG + col) * 3 + 1];
    }

    // ---- STREAM 32 corr rows (one contiguous 16,640B span) into LDS ----
    // 1040 float4; thread t covers g = t, t+256, t+512, t+768 (+16 tail)
    {
        size_t base4 = (size_t)nb * ROWF / 4;    // nb*130 divisible by 4
        const float4* srcv = (const float4*)corr;
        float4* dstv = (float4*)ldsCorr;
#pragma unroll
        for (int u = 0; u < 5; ++u) {
            int g = t + 256 * u;
            if (g < 1040 && (base4 + (size_t)g) < CORR_F4)
                dstv[g] = srcv[base4 + g];
        }
    }

    // ---- B fragment: B[k=khalf*8+j][n=col] = W2[k][col], bf16 RNE ----
    union FragU { short8 s8; __hip_bfloat162 h2[4]; };
    FragU bu;
#pragma unroll
    for (int p = 0; p < 4; ++p) {
        int k = khalf * 8 + 2 * p;
        bu.h2[p] = __float22bfloat162_rn(
            make_float2(W2[k * 32 + col], W2[(k + 1) * 32 + col]));
    }
    float b2c = b2[col];

    // ---- fold W_se@W1 (32) and b_se@W1+b1 (16): once per block ----
    if (t < 48) {
        float s;
        if (t < 32) {                       // fold[c*16+j] = Wc[c][j]
            int c = t >> 4, j = t & 15;
            s = 0.0f;
#pragma unroll
            for (int e = 0; e < 32; ++e)
                s = fmaf(W_se[c * 32 + e], W1[e * 16 + j], s);
        } else {                            // fold[32+j] = bc[j]
            int j = t - 32;
            s = b1[j];
#pragma unroll
            for (int e = 0; e < 32; ++e)
                s = fmaf(b_se[e], W1[e * 16 + j], s);
        }
        fold[t] = s;
    }

    __syncthreads();

    // ---- rel gathers now hit LDS (~120cyc, no HBM dependency) ----
    float2 rel[8];
#pragma unroll
    for (int i = 0; i < 8; ++i)
        rel[i] = *(const float2*)&ldsCorr[(w * 8 + i) * ROWF + 2 * idxv[i]];

    // ---- per-lane layer-1 weights for its 8 k's ----
    v2f wc0v[4], wc1v[4], bcv[4];
    {
        const float* fb = fold + khalf * 8;
#pragma unroll
        for (int p = 0; p < 4; ++p) {
            wc0v[p] = *(const v2f*)(fb + 2 * p);
            wc1v[p] = *(const v2f*)(fb + 16 + 2 * p);
            bcv[p]  = *(const v2f*)(fb + 32 + 2 * p);
        }
    }

    f32x16 czero;
#pragma unroll
    for (int j = 0; j < 16; ++j) czero[j] = 0.0f;

#pragma unroll
    for (int i = 0; i < 8; ++i) {
        int node = nbase + i;

        v2f r0s = {rel[i].x, rel[i].x}, r1s = {rel[i].y, rel[i].y};

        // layer 1 (f32): h1[k] = relu(r0*Wc0[k] + r1*Wc1[k] + bc[k]), 8 k's
        FragU au;
#pragma unroll
        for (int p = 0; p < 4; ++p) {
            v2f h = pk_max((v2f)(0.0f),
                     pk_fma(r0s, wc0v[p], pk_fma(r1s, wc1v[p], bcv[p])));
            au.h2[p] = __float22bfloat162_rn(make_float2(h.x, h.y));
        }

        // layer 2: D(32x32) = A(32x16) @ B(16x32), f32 accumulate
        f32x16 acc = __builtin_amdgcn_mfma_f32_32x32x16_bf16(au.s8, bu.s8, czero, 0, 0, 0);

        // max over this lane's 16 rows: packed tree (rows permute-invariant)
        v2f p0 = pk_max((v2f){acc[0],  acc[1]},  (v2f){acc[2],  acc[3]});
        v2f p1 = pk_max((v2f){acc[4],  acc[5]},  (v2f){acc[6],  acc[7]});
        v2f p2 = pk_max((v2f){acc[8],  acc[9]},  (v2f){acc[10], acc[11]});
        v2f p3 = pk_max((v2f){acc[12], acc[13]}, (v2f){acc[14], acc[15]});
        v2f q0 = pk_max(p0, p1);
        v2f q1 = pk_max(p2, p3);
        v2f rr = pk_max(q0, q1);
        float m = fmaxf(rr.x, rr.y);
        // other 16 rows live in the partner lane (same col, lane^32)
        m = fmaxf(m, __shfl_xor(m, 32, 64));

        float res = fmaxf(0.0f, m + b2c);    // b2 after max; relu/neginf fold
        if (lane < 32 && node < NODES)
            out[(size_t)node * 32 + col] = res;   // 128B per node, coalesced
    }
}

extern "C" void kernel_launch(void* const* d_in, const int* in_sizes, int n_in,
                              void* d_out, int out_size, void* d_ws, size_t ws_size,
                              hipStream_t stream) {
    const float* corr = (const float*)d_in[0];
    const int*   nei  = (const int*)d_in[1];
    // d_in[2] = lstm_state: dead input (unused by the reference output)
    const float* W_se = (const float*)d_in[3];
    const float* b_se = (const float*)d_in[4];
    const float* W1   = (const float*)d_in[5];
    const float* b1   = (const float*)d_in[6];
    const float* W2   = (const float*)d_in[7];
    const float* b2   = (const float*)d_in[8];
    float* out = (float*)d_out;

    int blocks = (NODES + 31) / 32;   // 32 nodes per block (4 waves x 8 nodes)
    hipLaunchKernelGGL(fused_kernel, dim3(blocks), dim3(256), 0, stream,
                       corr, nei, W_se, b_se, W1, b1, W2, b2, out);
}

// Round 11
// 103.055 us; speedup vs baseline: 1.0516x; 1.0516x over previous
//
#include <hip/hip_runtime.h>
#include <hip/hip_bf16.h>

#define NODES 50000
#define NA    65
#define NDEG  32

// Inputs f32 (R2 probe). Output f32.
// R11 = revert to R8 (best measured: 104.96us).
//   R8/R9/R10 falsified the VMEM-redundancy, barrier-coupling, and
//   dependent-gather-latency theories respectively (all deltas within
//   +-3us of 105). Cycle model bounds true kernel time at ~8-9us; the
//   rest of the measured total is the harness restore/poison floor
//   (~80us: 268MB ws fill at ~42us + d_in restore copies + launch/sync).
//   Structure: 1 MFMA (v_mfma_f32_32x32x16_bf16) per node, M=neighbors,
//   N=channels, K=hidden; layer 1 f32 VALU; direct per-lane gathers;
//   b2 after max; relu/neginf folded into max-with-0.

typedef float v2f __attribute__((ext_vector_type(2)));
typedef __attribute__((ext_vector_type(8))) short short8;     // 8 bf16 = 4 VGPRs
typedef __attribute__((ext_vector_type(16))) float f32x16;    // MFMA C/D

static __device__ __forceinline__ v2f pk_fma(v2f a, v2f b, v2f c) {
    return __builtin_elementwise_fma(a, b, c);
}
static __device__ __forceinline__ v2f pk_max(v2f a, v2f b) {
    return __builtin_elementwise_max(a, b);
}

__global__ __launch_bounds__(256, 1) void fused_kernel(
    const float* __restrict__ corr,   // (N, 65, 2)
    const int*   __restrict__ nei,    // (N, 32, 3)
    const float* __restrict__ W_se,   // (2, 32)
    const float* __restrict__ b_se,   // (32)
    const float* __restrict__ W1,     // (32, 16)
    const float* __restrict__ b1,     // (16)
    const float* __restrict__ W2,     // (16, 32)
    const float* __restrict__ b2,     // (32)
    float* __restrict__ out)          // (N, 32)
{
    __shared__ __align__(16) float fold[48];

    int t     = threadIdx.x;
    int lane  = t & 63;
    int w     = t >> 6;              // wave id: nodes w*8 .. w*8+7 of this block
    int col   = lane & 31;           // m (neighbor) for A, n (channel) for B/C
    int khalf = lane >> 5;           // k-chunk: 0 -> k 0..7, 1 -> k 8..15
    int nbase = blockIdx.x * 32 + w * 8;

    // ---- issue all 8 idx loads FIRST (independent, coalesced 384B span) ----
    int idxv[8];
#pragma unroll
    for (int i = 0; i < 8; ++i) {
        int node = nbase + i; if (node > NODES - 1) node = NODES - 1;
        idxv[i] = nei[((size_t)node * NDEG + col) * 3 + 1];
    }

    // ---- fold W_se@W1 (32) and b_se@W1+b1 (16); overlaps idx latency ----
    if (t < 48) {
        float s;
        if (t < 32) {                       // fold[c*16+j] = Wc[c][j]
            int c = t >> 4, j = t & 15;
            s = 0.0f;
#pragma unroll
            for (int e = 0; e < 32; ++e)
                s = fmaf(W_se[c * 32 + e], W1[e * 16 + j], s);
        } else {                            // fold[32+j] = bc[j]
            int j = t - 32;
            s = b1[j];
#pragma unroll
            for (int e = 0; e < 32; ++e)
                s = fmaf(b_se[e], W1[e * 16 + j], s);
        }
        fold[t] = s;
    }

    // ---- 8 independent rel gathers (each within one 520B corr row) ----
    float2 rel[8];
#pragma unroll
    for (int i = 0; i < 8; ++i) {
        int node = nbase + i; if (node > NODES - 1) node = NODES - 1;
        rel[i] = ((const float2*)corr)[(size_t)node * NA + idxv[i]];
    }

    // ---- B fragment: B[k=khalf*8+j][n=col] = W2[k][col], bf16 RNE ----
    union FragU { short8 s8; __hip_bfloat162 h2[4]; };
    FragU bu;
#pragma unroll
    for (int p = 0; p < 4; ++p) {
        int k = khalf * 8 + 2 * p;
        bu.h2[p] = __float22bfloat162_rn(
            make_float2(W2[k * 32 + col], W2[(k + 1) * 32 + col]));
    }
    float b2c = b2[col];

    __syncthreads();

    // ---- per-lane layer-1 weights for its 8 k's ----
    v2f wc0v[4], wc1v[4], bcv[4];
    {
        const float* fb = fold + khalf * 8;
#pragma unroll
        for (int p = 0; p < 4; ++p) {
            wc0v[p] = *(const v2f*)(fb + 2 * p);
            wc1v[p] = *(const v2f*)(fb + 16 + 2 * p);
            bcv[p]  = *(const v2f*)(fb + 32 + 2 * p);
        }
    }

    f32x16 czero;
#pragma unroll
    for (int j = 0; j < 16; ++j) czero[j] = 0.0f;

#pragma unroll
    for (int i = 0; i < 8; ++i) {
        int node = nbase + i;

        v2f r0s = {rel[i].x, rel[i].x}, r1s = {rel[i].y, rel[i].y};

        // layer 1 (f32): h1[k] = relu(r0*Wc0[k] + r1*Wc1[k] + bc[k]), 8 k's
        FragU au;
#pragma unroll
        for (int p = 0; p < 4; ++p) {
            v2f h = pk_max((v2f)(0.0f),
                     pk_fma(r0s, wc0v[p], pk_fma(r1s, wc1v[p], bcv[p])));
            au.h2[p] = __float22bfloat162_rn(make_float2(h.x, h.y));
        }

        // layer 2: D(32x32) = A(32x16) @ B(16x32), f32 accumulate
        f32x16 acc = __builtin_amdgcn_mfma_f32_32x32x16_bf16(au.s8, bu.s8, czero, 0, 0, 0);

        // max over this lane's 16 rows: packed tree (rows permute-invariant)
        v2f p0 = pk_max((v2f){acc[0],  acc[1]},  (v2f){acc[2],  acc[3]});
        v2f p1 = pk_max((v2f){acc[4],  acc[5]},  (v2f){acc[6],  acc[7]});
        v2f p2 = pk_max((v2f){acc[8],  acc[9]},  (v2f){acc[10], acc[11]});
        v2f p3 = pk_max((v2f){acc[12], acc[13]}, (v2f){acc[14], acc[15]});
        v2f q0 = pk_max(p0, p1);
        v2f q1 = pk_max(p2, p3);
        v2f rr = pk_max(q0, q1);
        float m = fmaxf(rr.x, rr.y);
        // other 16 rows live in the partner lane (same col, lane^32)
        m = fmaxf(m, __shfl_xor(m, 32, 64));

        float res = fmaxf(0.0f, m + b2c);    // b2 after max; relu/neginf fold
        if (lane < 32 && node < NODES)
            out[(size_t)node * 32 + col] = res;   // 128B per node, coalesced
    }
}

extern "C" void kernel_launch(void* const* d_in, const int* in_sizes, int n_in,
                              void* d_out, int out_size, void* d_ws, size_t ws_size,
                              hipStream_t stream) {
    const float* corr = (const float*)d_in[0];
    const int*   nei  = (const int*)d_in[1];
    // d_in[2] = lstm_state: dead input (unused by the reference output)
    const float* W_se = (const float*)d_in[3];
    const float* b_se = (const float*)d_in[4];
    const float* W1   = (const float*)d_in[5];
    const float* b1   = (const float*)d_in[6];
    const float* W2   = (const float*)d_in[7];
    const float* b2   = (const float*)d_in[8];
    float* out = (float*)d_out;

    int blocks = (NODES + 31) / 32;   // 32 nodes per block (4 waves x 8 nodes)
    hipLaunchKernelGGL(fused_kernel, dim3(blocks), dim3(256), 0, stream,
                       corr, nei, W_se, b_se, W1, b1, W2, b2, out);
}